// Round 14
// baseline (326.598 us; speedup 1.0000x reference)
//
#include <hip/hip_runtime.h>
#include <hip/hip_fp16.h>
#include <hip/hip_fp8.h>

#define NNODES 4096
#define LWALK 16
#define ODIM 8

#define FP8_SCALE 256.0f
#define FP8_INV   0.00390625f          // 1/256
#define FP8_INV2  1.52587890625e-05f   // 1/65536

typedef unsigned int uint4n __attribute__((ext_vector_type(4)));
typedef unsigned int uint2n __attribute__((ext_vector_type(2)));
typedef float float2n __attribute__((ext_vector_type(2)));

// ---------- fp8 helpers ----------
// decode 4 fp8 bytes (one dword) -> two packed float2
__device__ __forceinline__ void dec4x2(unsigned int w, float2n* lo, float2n* hi) {
#if __has_builtin(__builtin_amdgcn_cvt_pk_f32_fp8)
    *lo = __builtin_amdgcn_cvt_pk_f32_fp8((int)w, false);
    *hi = __builtin_amdgcn_cvt_pk_f32_fp8((int)w, true);
#else
    const unsigned char* b = (const unsigned char*)&w;
    __hip_fp8_e4m3 t0, t1, t2, t3;
    t0.__x = b[0]; t1.__x = b[1]; t2.__x = b[2]; t3.__x = b[3];
    float2n l, h;
    l.x = (float)t0; l.y = (float)t1;
    h.x = (float)t2; h.y = (float)t3;
    *lo = l; *hi = h;
#endif
}

__device__ __forceinline__ void dec8f(unsigned int lo, unsigned int hi, float* f) {
    float2n a, b, c, d;
    dec4x2(lo, &a, &b);
    dec4x2(hi, &c, &d);
    f[0] = a.x; f[1] = a.y; f[2] = b.x; f[3] = b.y;
    f[4] = c.x; f[5] = c.y; f[6] = d.x; f[7] = d.y;
}

__device__ __forceinline__ void enc8f(const float* a, unsigned int* lo,
                                      unsigned int* hi) {
#if __has_builtin(__builtin_amdgcn_cvt_pk_fp8_f32)
    int l = 0, h = 0;
    l = __builtin_amdgcn_cvt_pk_fp8_f32(a[0], a[1], l, false);
    l = __builtin_amdgcn_cvt_pk_fp8_f32(a[2], a[3], l, true);
    h = __builtin_amdgcn_cvt_pk_fp8_f32(a[4], a[5], h, false);
    h = __builtin_amdgcn_cvt_pk_fp8_f32(a[6], a[7], h, true);
    *lo = (unsigned int)l; *hi = (unsigned int)h;
#else
    unsigned char b[8];
#pragma unroll
    for (int i = 0; i < 8; ++i)
        b[i] = __hip_cvt_float_to_fp8(a[i], __HIP_SATFINITE, __HIP_E4M3);
    unsigned int w[2];
    __builtin_memcpy(w, b, 8);
    *lo = w[0]; *hi = w[1];
#endif
}

__device__ __forceinline__ void dec16f(uint4n w, float* f) {
    dec8f(w.x, w.y, f);
    dec8f(w.z, w.w, f + 8);
}

// ---------- edge-index dtype detection ----------
__global__ void detect_fmt_k(const void* ei, int E, int* flag) {
    if (blockIdx.x == 0 && threadIdx.x == 0) {
        const long long* p = (const long long*)ei;
        int ok = 1;
        for (int i = 0; i < 64; ++i) {
            long long v = p[i];
            if (v < 0 || v >= NNODES) { ok = 0; break; }
        }
        *flag = ok;
    }
}

__device__ __forceinline__ int load_idx(const void* p, int i, int fmt) {
    if (fmt) return (int)((const long long*)p)[i];
    return ((const int*)p)[i];
}

__global__ void build_deg_cnt_k(const void* ei, int E, int* deg, int* cnt,
                                const int* fmt) {
    int e = blockIdx.x * blockDim.x + threadIdx.x;
    if (e >= E) return;
    int f = *fmt;
    int r = load_idx(ei, e, f);
    int c = load_idx(ei, E + e, f);
    atomicAdd(&deg[r], 1);
    atomicAdd(&cnt[c], 1);
}

// ---------- exclusive scan over padded (multiple-of-4) counts ----------
__global__ void scan_k(const int* __restrict__ cnt, int* __restrict__ rowptr,
                       int* __restrict__ cursor) {
    __shared__ int sm[1024];
    int tid = threadIdx.x;
    int v0 = (cnt[4 * tid + 0] + 3) & ~3;
    int v1 = (cnt[4 * tid + 1] + 3) & ~3;
    int v2 = (cnt[4 * tid + 2] + 3) & ~3;
    int v3 = (cnt[4 * tid + 3] + 3) & ~3;
    int tsum = v0 + v1 + v2 + v3;
    sm[tid] = tsum;
    __syncthreads();
    int val = tsum;
    for (int off = 1; off < 1024; off <<= 1) {
        int t = (tid >= off) ? sm[tid - off] : 0;
        __syncthreads();
        val += t;
        sm[tid] = val;
        __syncthreads();
    }
    int excl = val - tsum;
    int p0 = excl, p1 = excl + v0, p2 = p1 + v1, p3 = p2 + v2;
    rowptr[4 * tid + 0] = p0; rowptr[4 * tid + 1] = p1;
    rowptr[4 * tid + 2] = p2; rowptr[4 * tid + 3] = p3;
    cursor[4 * tid + 0] = p0; cursor[4 * tid + 1] = p1;
    cursor[4 * tid + 2] = p2; cursor[4 * tid + 3] = p3;
    if (tid == 1023) rowptr[4096] = val;
}

__global__ void fill_csr_k(const void* ei, int E, const int* __restrict__ deg,
                           int* cursor, uint2* __restrict__ epad, const int* fmt) {
    int e = blockIdx.x * blockDim.x + threadIdx.x;
    if (e >= E) return;
    int f = *fmt;
    int r = load_idx(ei, e, f);
    int c = load_idx(ei, E + e, f);
    int pos = atomicAdd(&cursor[c], 1);
    int d = deg[r];
    float v = 1.0f / (float)(d < 1 ? 1 : d);
    epad[pos] = make_uint2((unsigned)r, __float_as_uint(v));
}

__global__ void pad_fill_k(const int* __restrict__ rowptr,
                           const int* __restrict__ cursor,
                           uint2* __restrict__ epad) {
    int c = blockIdx.x * blockDim.x + threadIdx.x;
    if (c >= NNODES) return;
    for (int p = cursor[c]; p < rowptr[c + 1]; ++p)
        epad[p] = make_uint2(0u, 0u);
}

// ---------- X2 = (P^T)^2 via two-level sparse CSR walk; diag k=1,2 fused ------
__global__ __launch_bounds__(256) void x2build_k(
    const int* __restrict__ rowptr, const uint2* __restrict__ epad,
    unsigned char* __restrict__ Y8, float* __restrict__ rw) {
    __shared__ float row[NNODES];
    __shared__ float dia1;
    const int c = blockIdx.x;
    const int t = threadIdx.x;
    for (int i = t; i < NNODES; i += 256) row[i] = 0.f;
    if (t == 0) dia1 = 0.f;
    __syncthreads();
    const int beg = rowptr[c], end = rowptr[c + 1];
    const int g = t >> 4;        // e1 slot [0,16)
    const int l = t & 15;        // e2 lane [0,16)
    for (int i1 = beg + g; i1 < end; i1 += 16) {
        uint2 e1 = epad[i1];
        float v = __uint_as_float(e1.y);
        if (v != 0.f) {
            int r = (int)e1.x;
            if (r == c && l == 0) atomicAdd(&dia1, v);
            int b2 = rowptr[r], n2 = rowptr[r + 1];
            for (int j = b2 + l; j < n2; j += 16) {
                uint2 e2 = epad[j];
                float w = __uint_as_float(e2.y);
                if (w != 0.f) atomicAdd(&row[e2.x], v * w);
            }
        }
    }
    __syncthreads();
    if (t == 0) {
        rw[c * LWALK + 0] = dia1;       // diag k=1 (exact fp32)
        rw[c * LWALK + 1] = row[c];     // diag k=2 (fp32, pre-quantize)
    }
    // accumulator is UNscaled here -> multiply by FP8_SCALE when encoding
    float f[16];
    const int base = t * 16;
#pragma unroll
    for (int u = 0; u < 16; ++u) f[u] = row[base + u] * FP8_SCALE;
    uint4n o;
    unsigned int lo, hi;
    enc8f(f, &lo, &hi);     o.x = lo; o.y = hi;
    enc8f(f + 8, &lo, &hi); o.z = lo; o.w = hi;
    __builtin_nontemporal_store(o, (uint4n*)(Y8 + (size_t)c * NNODES + base));
}

// ---------- shared pairdiag body (float LDS tiles, packed-f32 fma) ----------
__device__ __forceinline__ void pair_body(
    const unsigned char* __restrict__ PA, const unsigned char* __restrict__ PB,
    float* __restrict__ rw, int colO, int colE, int pb,
    float (*bt)[66], float (*ct)[66]) {
    const int i0 = (pb & 63) * 64;
    const int Jbeg = (pb >> 6) * (NNODES / 16);
    const int Jend = Jbeg + (NNODES / 16);
    const int t = threadIdx.x;
    const int li = t >> 2;
    const int q = t & 3;
    const int c0 = q * 16;
    float2n accO2 = {0.f, 0.f}, accE2 = {0.f, 0.f};
    for (int J = Jbeg; J < Jend; J += 64) {
        uint4n b16 = __builtin_nontemporal_load(
            (const uint4n*)(PB + (size_t)(J + li) * NNODES + i0 + c0));
        uint4n g16 = __builtin_nontemporal_load(
            (const uint4n*)(PA + (size_t)(J + li) * NNODES + i0 + c0));
        __syncthreads();
        float bf[16], gf[16];
        dec16f(b16, bf);
        dec16f(g16, gf);
#pragma unroll
        for (int s = 0; s < 16; ++s) {
            bt[c0 + s][li] = bf[s];
            ct[c0 + s][li] = gf[s];
        }
        __syncthreads();
        uint4n a16 = __builtin_nontemporal_load(
            (const uint4n*)(PA + (size_t)(i0 + li) * NNODES + J + c0));
        float2n af2[8];
#pragma unroll
        for (int u = 0; u < 4; ++u)
            dec4x2(a16[u], &af2[2 * u], &af2[2 * u + 1]);
        const float2n* brow = (const float2n*)&bt[li][c0];
        const float2n* crow = (const float2n*)&ct[li][c0];
#pragma unroll
        for (int s = 0; s < 8; ++s) {
            accO2 = af2[s] * brow[s] + accO2;
            accE2 = af2[s] * crow[s] + accE2;
        }
    }
    float accO = accO2.x + accO2.y;
    float accE = accE2.x + accE2.y;
    accO += __shfl_xor(accO, 1);
    accO += __shfl_xor(accO, 2);
    accE += __shfl_xor(accE, 1);
    accE += __shfl_xor(accE, 2);
    if (q == 0) {
        atomicAdd(&rw[(i0 + li) * LWALK + colO], accO * FP8_INV2);
        atomicAdd(&rw[(i0 + li) * LWALK + colE], accE * FP8_INV2);
    }
}

// ---------- fused fp8 SpMM (+optional pairdiag in appended blocks) ----------
__global__ __launch_bounds__(256) void fused8_k(
    const unsigned char* __restrict__ X8, unsigned char* __restrict__ Y8,
    const int* __restrict__ rowptr, const uint2* __restrict__ epad,
    float* __restrict__ rw, int kcol,
    const unsigned char* __restrict__ PA, const unsigned char* __restrict__ PB,
    int colO, int colE, int nspmm) {
    __shared__ float bt[64][66];
    __shared__ float ct[64][66];
    const int bid = blockIdx.x;
    if (bid < nspmm) {
        const int slab = bid & 3;
        const int lane = threadIdx.x & 63;
        const int c =
            __builtin_amdgcn_readfirstlane((bid >> 2) * 4 + (threadIdx.x >> 6));
        const int colo = slab * 1024 + lane * 16;  // fp8 byte offset
        const unsigned char* Xs = X8 + colo;
        const int beg = rowptr[c], end = rowptr[c + 1];  // padded %4
        float2n a2[8];
#pragma unroll
        for (int u = 0; u < 8; ++u) a2[u] = (float2n){0.f, 0.f};
        for (int e = beg; e < end; e += 4) {
            uint2 ed[4];
#pragma unroll
            for (int j = 0; j < 4; ++j) ed[j] = epad[e + j];
            uint4n x[4];
#pragma unroll
            for (int j = 0; j < 4; ++j)
                x[j] = *(const uint4n*)(Xs + (size_t)ed[j].x * NNODES);
#pragma unroll
            for (int j = 0; j < 4; ++j) {
                float v = __uint_as_float(ed[j].y);
                float2n v2 = {v, v};
#pragma unroll
                for (int u = 0; u < 4; ++u) {
                    float2n p0, p1;
                    dec4x2(x[j][u], &p0, &p1);
                    a2[2 * u]     = p0 * v2 + a2[2 * u];
                    a2[2 * u + 1] = p1 * v2 + a2[2 * u + 1];
                }
            }
        }
        if ((c >> 10) == slab && lane == ((c & 1023) >> 4)) {
            const int dsel = c & 15;
            float d = 0.f;
#pragma unroll
            for (int u = 0; u < 8; ++u)
                if ((dsel >> 1) == u) {
                    float2n tv = a2[u];
                    d = (dsel & 1) ? tv.y : tv.x;
                }
            rw[c * LWALK + kcol] = d * FP8_INV;
        }
        // accumulator is ALREADY in the x256-scaled domain (input was scaled):
        // store as-is, no extra FP8_SCALE. (R13 bug: double-scaling -> overflow)
        float f[16];
#pragma unroll
        for (int u = 0; u < 8; ++u) {
            f[2 * u] = a2[u].x;
            f[2 * u + 1] = a2[u].y;
        }
        uint4n o;
        unsigned int lo, hi;
        enc8f(f, &lo, &hi);     o.x = lo; o.y = hi;
        enc8f(f + 8, &lo, &hi); o.z = lo; o.w = hi;
        __builtin_nontemporal_store(o, (uint4n*)(Y8 + (size_t)c * NNODES + colo));
    } else {
        pair_body(PA, PB, rw, colO, colE, bid - nspmm, bt, ct);
    }
}

// ---------- final pairdiag (k=15,16) ----------
__global__ __launch_bounds__(256) void finale_k(
    const unsigned char* __restrict__ PA, const unsigned char* __restrict__ PB,
    float* __restrict__ rw) {
    __shared__ float bt[64][66];
    __shared__ float ct[64][66];
    pair_body(PA, PB, rw, 14, 15, blockIdx.x, bt, ct);
}

// ---------- final linear ----------
__global__ void linear_k(const float* __restrict__ rw, const float* __restrict__ W,
                         const float* __restrict__ b, float* __restrict__ out) {
    int i = blockIdx.x * blockDim.x + threadIdx.x;
    if (i >= NNODES * ODIM) return;
    int s = i >> 3, d = i & 7;
    float acc = b[d];
#pragma unroll
    for (int k = 0; k < LWALK; ++k)
        acc = fmaf(rw[s * LWALK + k], W[d * LWALK + k], acc);
    out[i] = acc;
}

extern "C" void kernel_launch(void* const* d_in, const int* in_sizes, int n_in,
                              void* d_out, int out_size, void* d_ws, size_t ws_size,
                              hipStream_t stream) {
    const void* ei = d_in[0];
    int E = in_sizes[0] / 2;
    const float* W = (const float*)d_in[2];
    const float* bias = (const float*)d_in[3];
    float* out = (float*)d_out;

    char* ws = (char*)d_ws;
    size_t off = 0;
    auto alloc = [&](size_t bytes) -> char* {
        char* p = ws + off;
        off = (off + bytes + 255) & ~(size_t)255;
        return p;
    };
    int* flag = (int*)alloc(4);
    int* deg = (int*)alloc(NNODES * 4);
    int* cnt = (int*)alloc(NNODES * 4);
    int* rowptr = (int*)alloc((NNODES + 1) * 4);
    int* cursor = (int*)alloc(NNODES * 4);
    uint2* epad = (uint2*)alloc(((size_t)E + 4 * NNODES) * 8);
    float* rw = (float*)alloc(NNODES * LWALK * 4);
    unsigned char* A = (unsigned char*)alloc((size_t)NNODES * NNODES);
    unsigned char* B = (unsigned char*)alloc((size_t)NNODES * NNODES);
    unsigned char* C = (unsigned char*)alloc((size_t)NNODES * NNODES);

    (void)hipMemsetAsync(deg, 0, NNODES * 4, stream);
    (void)hipMemsetAsync(cnt, 0, NNODES * 4, stream);
    (void)hipMemsetAsync(rw, 0, NNODES * LWALK * 4, stream);
    detect_fmt_k<<<1, 64, 0, stream>>>(ei, E, flag);
    build_deg_cnt_k<<<(E + 255) / 256, 256, 0, stream>>>(ei, E, deg, cnt, flag);
    scan_k<<<1, 1024, 0, stream>>>(cnt, rowptr, cursor);
    fill_csr_k<<<(E + 255) / 256, 256, 0, stream>>>(ei, E, deg, cursor, epad, flag);
    pad_fill_k<<<(NNODES + 255) / 256, 256, 0, stream>>>(rowptr, cursor, epad);

    // X2 (fp8, scaled) directly from the CSR; diags k=1,2 fused.
    x2build_k<<<NNODES, 256, 0, stream>>>(rowptr, epad, A, rw);

    // fp8 chain with fused pairdiags. Rotation: X2=A,X3=B,X4=C,X5=A,X6=B,X7=C,X8=A
    const int SG = 4096;
    fused8_k<<<SG, 256, 0, stream>>>(A, B, rowptr, epad, rw, 2, nullptr, nullptr, 0, 0, SG);            // X3
    fused8_k<<<SG, 256, 0, stream>>>(B, C, rowptr, epad, rw, 3, nullptr, nullptr, 0, 0, SG);            // X4
    fused8_k<<<SG, 256, 0, stream>>>(C, A, rowptr, epad, rw, 4, nullptr, nullptr, 0, 0, SG);            // X5
    fused8_k<<<SG + 1024, 256, 0, stream>>>(A, B, rowptr, epad, rw, 5, A, C, 8, 9, SG);                 // X6 + k9,10
    fused8_k<<<SG + 1024, 256, 0, stream>>>(B, C, rowptr, epad, rw, 6, B, A, 10, 11, SG);               // X7 + k11,12
    fused8_k<<<SG + 1024, 256, 0, stream>>>(C, A, rowptr, epad, rw, 7, C, B, 12, 13, SG);               // X8 + k13,14
    finale_k<<<1024, 256, 0, stream>>>(A, C, rw);                                                       // k15,16
    linear_k<<<(NNODES * ODIM + 255) / 256, 256, 0, stream>>>(rw, W, bias, out);
}

// Round 15
// 296.707 us; speedup vs baseline: 1.1007x; 1.1007x over previous
//
#include <hip/hip_runtime.h>
#include <hip/hip_fp16.h>
#include <hip/hip_fp8.h>

#define NNODES 4096
#define LWALK 16
#define ODIM 8

#define FP8_SCALE 256.0f
#define FP8_INV   0.00390625f          // 1/256
#define FP8_INV2  1.52587890625e-05f   // 1/65536

typedef unsigned int uint4n __attribute__((ext_vector_type(4)));
typedef unsigned int uint2n __attribute__((ext_vector_type(2)));
typedef float float2n __attribute__((ext_vector_type(2)));

// ---------- fp8 helpers ----------
__device__ __forceinline__ void dec4x2(unsigned int w, float2n* lo, float2n* hi) {
#if __has_builtin(__builtin_amdgcn_cvt_pk_f32_fp8)
    *lo = __builtin_amdgcn_cvt_pk_f32_fp8((int)w, false);
    *hi = __builtin_amdgcn_cvt_pk_f32_fp8((int)w, true);
#else
    const unsigned char* b = (const unsigned char*)&w;
    __hip_fp8_e4m3 t0, t1, t2, t3;
    t0.__x = b[0]; t1.__x = b[1]; t2.__x = b[2]; t3.__x = b[3];
    float2n l, h;
    l.x = (float)t0; l.y = (float)t1;
    h.x = (float)t2; h.y = (float)t3;
    *lo = l; *hi = h;
#endif
}

__device__ __forceinline__ void dec8f(unsigned int lo, unsigned int hi, float* f) {
    float2n a, b, c, d;
    dec4x2(lo, &a, &b);
    dec4x2(hi, &c, &d);
    f[0] = a.x; f[1] = a.y; f[2] = b.x; f[3] = b.y;
    f[4] = c.x; f[5] = c.y; f[6] = d.x; f[7] = d.y;
}

__device__ __forceinline__ void enc8f(const float* a, unsigned int* lo,
                                      unsigned int* hi) {
#if __has_builtin(__builtin_amdgcn_cvt_pk_fp8_f32)
    int l = 0, h = 0;
    l = __builtin_amdgcn_cvt_pk_fp8_f32(a[0], a[1], l, false);
    l = __builtin_amdgcn_cvt_pk_fp8_f32(a[2], a[3], l, true);
    h = __builtin_amdgcn_cvt_pk_fp8_f32(a[4], a[5], h, false);
    h = __builtin_amdgcn_cvt_pk_fp8_f32(a[6], a[7], h, true);
    *lo = (unsigned int)l; *hi = (unsigned int)h;
#else
    unsigned char b[8];
#pragma unroll
    for (int i = 0; i < 8; ++i)
        b[i] = __hip_cvt_float_to_fp8(a[i], __HIP_SATFINITE, __HIP_E4M3);
    unsigned int w[2];
    __builtin_memcpy(w, b, 8);
    *lo = w[0]; *hi = w[1];
#endif
}

__device__ __forceinline__ void dec16f(uint4n w, float* f) {
    dec8f(w.x, w.y, f);
    dec8f(w.z, w.w, f + 8);
}

// ---------- edge-index dtype detection ----------
__global__ void detect_fmt_k(const void* ei, int E, int* flag) {
    if (blockIdx.x == 0 && threadIdx.x == 0) {
        const long long* p = (const long long*)ei;
        int ok = 1;
        for (int i = 0; i < 64; ++i) {
            long long v = p[i];
            if (v < 0 || v >= NNODES) { ok = 0; break; }
        }
        *flag = ok;
    }
}

__device__ __forceinline__ int load_idx(const void* p, int i, int fmt) {
    if (fmt) return (int)((const long long*)p)[i];
    return ((const int*)p)[i];
}

__global__ void build_deg_cnt_k(const void* ei, int E, int* deg, int* cnt,
                                const int* fmt) {
    int e = blockIdx.x * blockDim.x + threadIdx.x;
    if (e >= E) return;
    int f = *fmt;
    int r = load_idx(ei, e, f);
    int c = load_idx(ei, E + e, f);
    atomicAdd(&deg[r], 1);
    atomicAdd(&cnt[c], 1);
}

// ---------- exclusive scan over padded (multiple-of-4) counts ----------
__global__ void scan_k(const int* __restrict__ cnt, int* __restrict__ rowptr,
                       int* __restrict__ cursor) {
    __shared__ int sm[1024];
    int tid = threadIdx.x;
    int v0 = (cnt[4 * tid + 0] + 3) & ~3;
    int v1 = (cnt[4 * tid + 1] + 3) & ~3;
    int v2 = (cnt[4 * tid + 2] + 3) & ~3;
    int v3 = (cnt[4 * tid + 3] + 3) & ~3;
    int tsum = v0 + v1 + v2 + v3;
    sm[tid] = tsum;
    __syncthreads();
    int val = tsum;
    for (int off = 1; off < 1024; off <<= 1) {
        int t = (tid >= off) ? sm[tid - off] : 0;
        __syncthreads();
        val += t;
        sm[tid] = val;
        __syncthreads();
    }
    int excl = val - tsum;
    int p0 = excl, p1 = excl + v0, p2 = p1 + v1, p3 = p2 + v2;
    rowptr[4 * tid + 0] = p0; rowptr[4 * tid + 1] = p1;
    rowptr[4 * tid + 2] = p2; rowptr[4 * tid + 3] = p3;
    cursor[4 * tid + 0] = p0; cursor[4 * tid + 1] = p1;
    cursor[4 * tid + 2] = p2; cursor[4 * tid + 3] = p3;
    if (tid == 1023) rowptr[4096] = val;
}

__global__ void fill_csr_k(const void* ei, int E, const int* __restrict__ deg,
                           int* cursor, uint2* __restrict__ epad, const int* fmt) {
    int e = blockIdx.x * blockDim.x + threadIdx.x;
    if (e >= E) return;
    int f = *fmt;
    int r = load_idx(ei, e, f);
    int c = load_idx(ei, E + e, f);
    int pos = atomicAdd(&cursor[c], 1);
    int d = deg[r];
    float v = 1.0f / (float)(d < 1 ? 1 : d);
    epad[pos] = make_uint2((unsigned)r, __float_as_uint(v));
}

__global__ void pad_fill_k(const int* __restrict__ rowptr,
                           const int* __restrict__ cursor,
                           uint2* __restrict__ epad) {
    int c = blockIdx.x * blockDim.x + threadIdx.x;
    if (c >= NNODES) return;
    for (int p = cursor[c]; p < rowptr[c + 1]; ++p)
        epad[p] = make_uint2(0u, 0u);
}

// ---------- X2 = (P^T)^2 via two-level sparse CSR walk; diag k=1,2 fused ------
__global__ __launch_bounds__(256) void x2build_k(
    const int* __restrict__ rowptr, const uint2* __restrict__ epad,
    unsigned char* __restrict__ Y8, float* __restrict__ rw) {
    __shared__ float row[NNODES];
    __shared__ float dia1;
    const int c = blockIdx.x;
    const int t = threadIdx.x;
    for (int i = t; i < NNODES; i += 256) row[i] = 0.f;
    if (t == 0) dia1 = 0.f;
    __syncthreads();
    const int beg = rowptr[c], end = rowptr[c + 1];
    const int g = t >> 4;        // e1 slot [0,16)
    const int l = t & 15;        // e2 lane [0,16)
    for (int i1 = beg + g; i1 < end; i1 += 16) {
        uint2 e1 = epad[i1];
        float v = __uint_as_float(e1.y);
        if (v != 0.f) {
            int r = (int)e1.x;
            if (r == c && l == 0) atomicAdd(&dia1, v);
            int b2 = rowptr[r], n2 = rowptr[r + 1];
            for (int j = b2 + l; j < n2; j += 16) {
                uint2 e2 = epad[j];
                float w = __uint_as_float(e2.y);
                if (w != 0.f) atomicAdd(&row[e2.x], v * w);
            }
        }
    }
    __syncthreads();
    if (t == 0) {
        rw[c * LWALK + 0] = dia1;       // diag k=1 (exact fp32)
        rw[c * LWALK + 1] = row[c];     // diag k=2 (fp32, pre-quantize)
    }
    // accumulator is UNscaled here -> multiply by FP8_SCALE when encoding
    float f[16];
    const int base = t * 16;
#pragma unroll
    for (int u = 0; u < 16; ++u) f[u] = row[base + u] * FP8_SCALE;
    uint4n o;
    unsigned int lo, hi;
    enc8f(f, &lo, &hi);     o.x = lo; o.y = hi;
    enc8f(f + 8, &lo, &hi); o.z = lo; o.w = hi;
    __builtin_nontemporal_store(o, (uint4n*)(Y8 + (size_t)c * NNODES + base));
}

// ---------- shared pairdiag body (HALF LDS tiles - keeps LDS at 16.9KB) ------
__device__ __forceinline__ void pair_body(
    const unsigned char* __restrict__ PA, const unsigned char* __restrict__ PB,
    float* __restrict__ rw, int colO, int colE, int pb,
    __half (*bt)[66], __half (*ct)[66]) {
    const int i0 = (pb & 63) * 64;
    const int Jbeg = (pb >> 6) * (NNODES / 16);
    const int Jend = Jbeg + (NNODES / 16);
    const int t = threadIdx.x;
    const int li = t >> 2;
    const int q = t & 3;
    const int c0 = q * 16;
    float accO = 0.f, accE = 0.f;
    for (int J = Jbeg; J < Jend; J += 64) {
        uint4n b16 = __builtin_nontemporal_load(
            (const uint4n*)(PB + (size_t)(J + li) * NNODES + i0 + c0));
        uint4n g16 = __builtin_nontemporal_load(
            (const uint4n*)(PA + (size_t)(J + li) * NNODES + i0 + c0));
        __syncthreads();
        float bf[16], gf[16];
        dec16f(b16, bf);
        dec16f(g16, gf);
#pragma unroll
        for (int s = 0; s < 16; ++s) {
            bt[c0 + s][li] = __float2half(bf[s]);  // fp8 values exact in fp16
            ct[c0 + s][li] = __float2half(gf[s]);
        }
        __syncthreads();
        uint4n a16 = __builtin_nontemporal_load(
            (const uint4n*)(PA + (size_t)(i0 + li) * NNODES + J + c0));
        float af[16];
        dec16f(a16, af);
#pragma unroll
        for (int s = 0; s < 16; ++s) {
            accO = fmaf(af[s], __half2float(bt[li][c0 + s]), accO);
            accE = fmaf(af[s], __half2float(ct[li][c0 + s]), accE);
        }
    }
    accO += __shfl_xor(accO, 1);
    accO += __shfl_xor(accO, 2);
    accE += __shfl_xor(accE, 1);
    accE += __shfl_xor(accE, 2);
    if (q == 0) {
        atomicAdd(&rw[(i0 + li) * LWALK + colO], accO * FP8_INV2);
        atomicAdd(&rw[(i0 + li) * LWALK + colE], accE * FP8_INV2);
    }
}

// ---------- fused fp8 SpMM (+optional pairdiag in appended blocks) ----------
__global__ __launch_bounds__(256) void fused8_k(
    const unsigned char* __restrict__ X8, unsigned char* __restrict__ Y8,
    const int* __restrict__ rowptr, const uint2* __restrict__ epad,
    float* __restrict__ rw, int kcol,
    const unsigned char* __restrict__ PA, const unsigned char* __restrict__ PB,
    int colO, int colE, int nspmm) {
    __shared__ __half bt[64][66];
    __shared__ __half ct[64][66];
    const int bid = blockIdx.x;
    if (bid < nspmm) {
        const int slab = bid & 3;
        const int lane = threadIdx.x & 63;
        const int c =
            __builtin_amdgcn_readfirstlane((bid >> 2) * 4 + (threadIdx.x >> 6));
        const int colo = slab * 1024 + lane * 16;  // fp8 byte offset
        const unsigned char* Xs = X8 + colo;
        const int beg = rowptr[c], end = rowptr[c + 1];  // padded %4
        float2n a2[8];
#pragma unroll
        for (int u = 0; u < 8; ++u) a2[u] = (float2n){0.f, 0.f};
        for (int e = beg; e < end; e += 4) {
            uint2 ed[4];
#pragma unroll
            for (int j = 0; j < 4; ++j) ed[j] = epad[e + j];
            uint4n x[4];
#pragma unroll
            for (int j = 0; j < 4; ++j)
                x[j] = *(const uint4n*)(Xs + (size_t)ed[j].x * NNODES);
#pragma unroll
            for (int j = 0; j < 4; ++j) {
                float v = __uint_as_float(ed[j].y);
                float2n v2 = {v, v};
#pragma unroll
                for (int u = 0; u < 4; ++u) {
                    float2n p0, p1;
                    dec4x2(x[j][u], &p0, &p1);
                    a2[2 * u]     = p0 * v2 + a2[2 * u];
                    a2[2 * u + 1] = p1 * v2 + a2[2 * u + 1];
                }
            }
        }
        if ((c >> 10) == slab && lane == ((c & 1023) >> 4)) {
            const int dsel = c & 15;
            float d = 0.f;
#pragma unroll
            for (int u = 0; u < 8; ++u)
                if ((dsel >> 1) == u) {
                    float2n tv = a2[u];
                    d = (dsel & 1) ? tv.y : tv.x;
                }
            rw[c * LWALK + kcol] = d * FP8_INV;
        }
        // accumulator is already in the x256-scaled domain: store as-is.
        float f[16];
#pragma unroll
        for (int u = 0; u < 8; ++u) {
            f[2 * u] = a2[u].x;
            f[2 * u + 1] = a2[u].y;
        }
        uint4n o;
        unsigned int lo, hi;
        enc8f(f, &lo, &hi);     o.x = lo; o.y = hi;
        enc8f(f + 8, &lo, &hi); o.z = lo; o.w = hi;
        __builtin_nontemporal_store(o, (uint4n*)(Y8 + (size_t)c * NNODES + colo));
    } else {
        pair_body(PA, PB, rw, colO, colE, bid - nspmm, bt, ct);
    }
}

// ---------- final pairdiag (k=15,16) ----------
__global__ __launch_bounds__(256) void finale_k(
    const unsigned char* __restrict__ PA, const unsigned char* __restrict__ PB,
    float* __restrict__ rw) {
    __shared__ __half bt[64][66];
    __shared__ __half ct[64][66];
    pair_body(PA, PB, rw, 14, 15, blockIdx.x, bt, ct);
}

// ---------- final linear ----------
__global__ void linear_k(const float* __restrict__ rw, const float* __restrict__ W,
                         const float* __restrict__ b, float* __restrict__ out) {
    int i = blockIdx.x * blockDim.x + threadIdx.x;
    if (i >= NNODES * ODIM) return;
    int s = i >> 3, d = i & 7;
    float acc = b[d];
#pragma unroll
    for (int k = 0; k < LWALK; ++k)
        acc = fmaf(rw[s * LWALK + k], W[d * LWALK + k], acc);
    out[i] = acc;
}

extern "C" void kernel_launch(void* const* d_in, const int* in_sizes, int n_in,
                              void* d_out, int out_size, void* d_ws, size_t ws_size,
                              hipStream_t stream) {
    const void* ei = d_in[0];
    int E = in_sizes[0] / 2;
    const float* W = (const float*)d_in[2];
    const float* bias = (const float*)d_in[3];
    float* out = (float*)d_out;

    char* ws = (char*)d_ws;
    size_t off = 0;
    auto alloc = [&](size_t bytes) -> char* {
        char* p = ws + off;
        off = (off + bytes + 255) & ~(size_t)255;
        return p;
    };
    int* flag = (int*)alloc(4);
    int* deg = (int*)alloc(NNODES * 4);
    int* cnt = (int*)alloc(NNODES * 4);
    int* rowptr = (int*)alloc((NNODES + 1) * 4);
    int* cursor = (int*)alloc(NNODES * 4);
    uint2* epad = (uint2*)alloc(((size_t)E + 4 * NNODES) * 8);
    float* rw = (float*)alloc(NNODES * LWALK * 4);
    unsigned char* A = (unsigned char*)alloc((size_t)NNODES * NNODES);
    unsigned char* B = (unsigned char*)alloc((size_t)NNODES * NNODES);
    unsigned char* C = (unsigned char*)alloc((size_t)NNODES * NNODES);

    (void)hipMemsetAsync(deg, 0, NNODES * 4, stream);
    (void)hipMemsetAsync(cnt, 0, NNODES * 4, stream);
    (void)hipMemsetAsync(rw, 0, NNODES * LWALK * 4, stream);
    detect_fmt_k<<<1, 64, 0, stream>>>(ei, E, flag);
    build_deg_cnt_k<<<(E + 255) / 256, 256, 0, stream>>>(ei, E, deg, cnt, flag);
    scan_k<<<1, 1024, 0, stream>>>(cnt, rowptr, cursor);
    fill_csr_k<<<(E + 255) / 256, 256, 0, stream>>>(ei, E, deg, cursor, epad, flag);
    pad_fill_k<<<(NNODES + 255) / 256, 256, 0, stream>>>(rowptr, cursor, epad);

    // X2 (fp8, scaled) directly from the CSR; diags k=1,2 fused.
    x2build_k<<<NNODES, 256, 0, stream>>>(rowptr, epad, A, rw);

    // fp8 chain with fused pairdiags. Rotation: X2=A,X3=B,X4=C,X5=A,X6=B,X7=C,X8=A
    const int SG = 4096;
    fused8_k<<<SG, 256, 0, stream>>>(A, B, rowptr, epad, rw, 2, nullptr, nullptr, 0, 0, SG);            // X3
    fused8_k<<<SG, 256, 0, stream>>>(B, C, rowptr, epad, rw, 3, nullptr, nullptr, 0, 0, SG);            // X4
    fused8_k<<<SG, 256, 0, stream>>>(C, A, rowptr, epad, rw, 4, nullptr, nullptr, 0, 0, SG);            // X5
    fused8_k<<<SG + 1024, 256, 0, stream>>>(A, B, rowptr, epad, rw, 5, A, C, 8, 9, SG);                 // X6 + k9,10
    fused8_k<<<SG + 1024, 256, 0, stream>>>(B, C, rowptr, epad, rw, 6, B, A, 10, 11, SG);               // X7 + k11,12
    fused8_k<<<SG + 1024, 256, 0, stream>>>(C, A, rowptr, epad, rw, 7, C, B, 12, 13, SG);               // X8 + k13,14
    finale_k<<<1024, 256, 0, stream>>>(A, C, rw);                                                       // k15,16
    linear_k<<<(NNODES * ODIM + 255) / 256, 256, 0, stream>>>(rw, W, bias, out);
}